// Round 2
// baseline (235.521 us; speedup 1.0000x reference)
//
#include <hip/hip_runtime.h>

#define NNODES 128
#define BATCH  32768
#define BLOCK  256
#define ROWS_PER_CHUNK 16
#define NCHUNKS (BATCH / ROWS_PER_CHUNK)   // 2048
#define GRID   1024

__device__ __forceinline__ float sigmoidf_(float z) {
    return 1.0f / (1.0f + __expf(-z));
}

__device__ __forceinline__ float clipf_(float v) {
    return fminf(fmaxf(v, -100.0f), 100.0f);
}

__device__ __forceinline__ unsigned short bf16_(float f) {
    unsigned u = __float_as_uint(f);
    return (unsigned short)((u + 0x8000u) >> 16);   // round-to-nearest-ish
}

// Per-node epilogue: 8 clipped states + node_input + params -> 8 derivatives.
__device__ __forceinline__ void node_update(const float* xs8, float ni,
                                            const float* gi, const float* invTi,
                                            float sci, float Ri, float* f8) {
    float S0 = sigmoidf_(Ri * xs8[0]) - 0.5f;
    float S2 = sigmoidf_(Ri * xs8[2]) - 0.5f;
    float S4 = sigmoidf_(Ri * xs8[4]) - 0.5f;
    float S6 = sigmoidf_(Ri * xs8[6]) - 0.5f;
    float u1 = ni - gi[0] * S0 - gi[1] * S2 - gi[2]  * S4;
    float u3 = ni + gi[7] * S0 - gi[6] * S2 - gi[11] * S4;
    float u5 = ni + gi[4] * S0 + gi[10] * S2 - gi[3] * S4 + gi[5] * S6;
    float u7 = ni - gi[8] * S4 - gi[9] * S6;
    f8[0] = sci * xs8[1];
    f8[1] = sci * (u1 - 2.0f * xs8[1] - xs8[0] * invTi[0]) * invTi[0];
    f8[2] = sci * xs8[3];
    f8[3] = sci * (u3 - 2.0f * xs8[3] - xs8[2] * invTi[1]) * invTi[1];
    f8[4] = sci * xs8[5];
    f8[5] = sci * (u5 - 2.0f * xs8[5] - xs8[4] * invTi[2]) * invTi[2];
    f8[6] = sci * xs8[7];
    f8[7] = sci * (u7 - 2.0f * xs8[7] - xs8[6] * invTi[3]) * invTi[3];
}

__global__ __launch_bounds__(BLOCK, 4)
void cmc_kernel(const float* __restrict__ x,
                const float* __restrict__ C,
                const float* __restrict__ G,
                const float* __restrict__ T,
                const float* __restrict__ adap,
                const float* __restrict__ R,
                float* __restrict__ out)
{
    // ct16[j*128 + (i ^ ((j&15)<<2))] = bf16(C[i][j]), diag zeroed.
    // XOR swizzle keeps 4-element groups 8B-aligned, spreads banks:
    // reads are 2-way (free), staging writes ~8-way (once per block).
    __shared__ unsigned short ct16[NNODES * NNODES];   // 32 KB
    __shared__ float m_lds[ROWS_PER_CHUNK][NNODES];    //  8 KB  (total 40 KB -> 4 blocks/CU)

    const int tid    = threadIdx.x;
    const int lane31 = tid & 31;
    const int lr     = tid >> 5;          // 0..7 (half-wave id)
    const int n0     = lane31 * 4;        // this thread's 4 nodes

    // ---- stage Ct once per block: 4x4 tile transpose, f32 -> bf16 ----
    {
        const int j0 = (tid & 31) * 4;    // j-tile (coalesced source reads)
        const int tb = tid >> 5;
        #pragma unroll
        for (int it = 0; it < 4; ++it) {
            const int i0 = (tb + it * 8) * 4;
            float4 row[4];
            #pragma unroll
            for (int r = 0; r < 4; ++r)
                row[r] = *reinterpret_cast<const float4*>(C + (size_t)(i0 + r) * NNODES + j0);
            #pragma unroll
            for (int k = 0; k < 4; ++k) {
                const int j = j0 + k;
                ushort4 w;
                w.x = (i0 + 0 == j) ? (unsigned short)0 : bf16_((&row[0].x)[k]);
                w.y = (i0 + 1 == j) ? (unsigned short)0 : bf16_((&row[1].x)[k]);
                w.z = (i0 + 2 == j) ? (unsigned short)0 : bf16_((&row[2].x)[k]);
                w.w = (i0 + 3 == j) ? (unsigned short)0 : bf16_((&row[3].x)[k]);
                const int col = i0 ^ ((j & 15) << 2);
                *reinterpret_cast<ushort4*>(&ct16[j * NNODES + col]) = w;
            }
        }
    }

    // ---- per-node params into registers (reused across chunks) ----
    float g[4][12], invT[4][4], sc[4], Rr[4];
    #pragma unroll
    for (int i = 0; i < 4; ++i) {
        int n = n0 + i;
        #pragma unroll
        for (int k = 0; k < 12; ++k) g[i][k] = G[n * 12 + k];
        #pragma unroll
        for (int k = 0; k < 4; ++k) invT[i][k] = 1.0f / T[n * 4 + k];
        sc[i] = 0.1f * sigmoidf_(adap[n]);
        Rr[i] = R[n];
    }

    __syncthreads();   // ct16 visible to all waves (only barrier in the kernel)

    for (int chunk = blockIdx.x; chunk < NCHUNKS; chunk += GRID) {
        const int r0 = chunk * ROWS_PER_CHUNK + lr;
        const int r1 = r0 + 8;

        // ---- load + clip x: 2 rows x 4 nodes x 8 states ----
        float xv[2][32];
        {
            const float4* p0 = reinterpret_cast<const float4*>(x + (size_t)r0 * 1024 + n0 * 8);
            const float4* p1 = reinterpret_cast<const float4*>(x + (size_t)r1 * 1024 + n0 * 8);
            #pragma unroll
            for (int q = 0; q < 8; ++q) {
                float4 v = p0[q];
                xv[0][q * 4 + 0] = clipf_(v.x); xv[0][q * 4 + 1] = clipf_(v.y);
                xv[0][q * 4 + 2] = clipf_(v.z); xv[0][q * 4 + 3] = clipf_(v.w);
            }
            #pragma unroll
            for (int q = 0; q < 8; ++q) {
                float4 v = p1[q];
                xv[1][q * 4 + 0] = clipf_(v.x); xv[1][q * 4 + 1] = clipf_(v.y);
                xv[1][q * 4 + 2] = clipf_(v.z); xv[1][q * 4 + 3] = clipf_(v.w);
            }
        }

        // ---- node means -> LDS (intra-half-wave exchange: no barrier needed;
        //      rows lr / lr+8 are written and read only by this half-wave) ----
        {
            float4 ma, mb;
            float* pa = &ma.x; float* pb = &mb.x;
            #pragma unroll
            for (int i = 0; i < 4; ++i) {
                float s0 = 0.0f, s1 = 0.0f;
                #pragma unroll
                for (int k = 0; k < 8; ++k) { s0 += xv[0][i * 8 + k]; s1 += xv[1][i * 8 + k]; }
                pa[i] = s0 * 0.125f; pb[i] = s1 * 0.125f;
            }
            *reinterpret_cast<float4*>(&m_lds[lr][n0])     = ma;
            *reinterpret_cast<float4*>(&m_lds[lr + 8][n0]) = mb;
        }

        // ---- node_input: acc[i] = sum_j m[r][j] * Ct[j][n0+i] ----
        float acc0[4] = {0, 0, 0, 0}, acc1[4] = {0, 0, 0, 0};
        #pragma unroll 8
        for (int j4 = 0; j4 < 32; ++j4) {
            float4 mA = *reinterpret_cast<const float4*>(&m_lds[lr][j4 * 4]);
            float4 mB = *reinterpret_cast<const float4*>(&m_lds[lr + 8][j4 * 4]);
            const float* pmA = &mA.x; const float* pmB = &mB.x;
            #pragma unroll
            for (int c2 = 0; c2 < 4; ++c2) {
                const int j = j4 * 4 + c2;
                const int col = n0 ^ ((j & 15) << 2);
                uint2 cu = *reinterpret_cast<const uint2*>(&ct16[j * NNODES + col]);
                float cv0 = __uint_as_float(cu.x << 16);
                float cv1 = __uint_as_float(cu.x & 0xffff0000u);
                float cv2 = __uint_as_float(cu.y << 16);
                float cv3 = __uint_as_float(cu.y & 0xffff0000u);
                float mv0 = pmA[c2], mv1 = pmB[c2];
                acc0[0] = fmaf(mv0, cv0, acc0[0]);
                acc0[1] = fmaf(mv0, cv1, acc0[1]);
                acc0[2] = fmaf(mv0, cv2, acc0[2]);
                acc0[3] = fmaf(mv0, cv3, acc0[3]);
                acc1[0] = fmaf(mv1, cv0, acc1[0]);
                acc1[1] = fmaf(mv1, cv1, acc1[1]);
                acc1[2] = fmaf(mv1, cv2, acc1[2]);
                acc1[3] = fmaf(mv1, cv3, acc1[3]);
            }
        }

        // ---- epilogue + store ----
        {
            float* o0 = out + (size_t)r0 * 1024 + n0 * 8;
            float* o1 = out + (size_t)r1 * 1024 + n0 * 8;
            #pragma unroll
            for (int i = 0; i < 4; ++i) {
                float f8[8];
                node_update(&xv[0][i * 8], acc0[i], g[i], invT[i], sc[i], Rr[i], f8);
                *reinterpret_cast<float4*>(o0 + i * 8)     = make_float4(f8[0], f8[1], f8[2], f8[3]);
                *reinterpret_cast<float4*>(o0 + i * 8 + 4) = make_float4(f8[4], f8[5], f8[6], f8[7]);
            }
            #pragma unroll
            for (int i = 0; i < 4; ++i) {
                float f8[8];
                node_update(&xv[1][i * 8], acc1[i], g[i], invT[i], sc[i], Rr[i], f8);
                *reinterpret_cast<float4*>(o1 + i * 8)     = make_float4(f8[0], f8[1], f8[2], f8[3]);
                *reinterpret_cast<float4*>(o1 + i * 8 + 4) = make_float4(f8[4], f8[5], f8[6], f8[7]);
            }
        }
        // no barrier: m_lds WAR across chunks is same-wave, handled by lgkmcnt
    }
}

extern "C" void kernel_launch(void* const* d_in, const int* in_sizes, int n_in,
                              void* d_out, int out_size, void* d_ws, size_t ws_size,
                              hipStream_t stream) {
    // setup_inputs order: t, x, node_connectivity, G, T, adaptation, R
    const float* x    = (const float*)d_in[1];
    const float* C    = (const float*)d_in[2];
    const float* G    = (const float*)d_in[3];
    const float* T    = (const float*)d_in[4];
    const float* adap = (const float*)d_in[5];
    const float* R    = (const float*)d_in[6];
    float* out        = (float*)d_out;

    hipLaunchKernelGGL(cmc_kernel, dim3(GRID), dim3(BLOCK), 0, stream,
                       x, C, G, T, adap, R, out);
}

// Round 3
// 107.770 us; speedup vs baseline: 2.1854x; 2.1854x over previous
//
#include <hip/hip_runtime.h>

#define NNODES 128
#define BATCH  32768
#define BLOCK  256
#define ROWS_PER_CHUNK 16
#define NCHUNKS (BATCH / ROWS_PER_CHUNK)   // 2048
#define GRID   1024

__device__ __forceinline__ float sigmoidf_(float z) {
    return 1.0f / (1.0f + __expf(-z));
}

__device__ __forceinline__ float clipf_(float v) {
    return fminf(fmaxf(v, -100.0f), 100.0f);
}

__device__ __forceinline__ unsigned short bf16_(float f) {
    unsigned u = __float_as_uint(f);
    return (unsigned short)((u + 0x8000u) >> 16);
}

// Per-node epilogue: 8 clipped states + node_input + params -> 8 derivatives.
__device__ __forceinline__ void node_update(const float* xs8, float ni,
                                            const float* gi, const float* invTi,
                                            float sci, float Ri, float* f8) {
    float S0 = sigmoidf_(Ri * xs8[0]) - 0.5f;
    float S2 = sigmoidf_(Ri * xs8[2]) - 0.5f;
    float S4 = sigmoidf_(Ri * xs8[4]) - 0.5f;
    float S6 = sigmoidf_(Ri * xs8[6]) - 0.5f;
    float u1 = ni - gi[0] * S0 - gi[1] * S2 - gi[2]  * S4;
    float u3 = ni + gi[7] * S0 - gi[6] * S2 - gi[11] * S4;
    float u5 = ni + gi[4] * S0 + gi[10] * S2 - gi[3] * S4 + gi[5] * S6;
    float u7 = ni - gi[8] * S4 - gi[9] * S6;
    f8[0] = sci * xs8[1];
    f8[1] = sci * (u1 - 2.0f * xs8[1] - xs8[0] * invTi[0]) * invTi[0];
    f8[2] = sci * xs8[3];
    f8[3] = sci * (u3 - 2.0f * xs8[3] - xs8[2] * invTi[1]) * invTi[1];
    f8[4] = sci * xs8[5];
    f8[5] = sci * (u5 - 2.0f * xs8[5] - xs8[4] * invTi[2]) * invTi[2];
    f8[6] = sci * xs8[7];
    f8[7] = sci * (u7 - 2.0f * xs8[7] - xs8[6] * invTi[3]) * invTi[3];
}

// launch_bounds(256,2): R2's (256,4) clamped the allocator to 64 VGPR and
// spilled ~70 regs to scratch (WRITE_SIZE 441 MB). (256,2) gives the 128-VGPR
// budget; actual usage ~124 lands in the 16-waves/CU quantum, and the 40 KB
// LDS then allows 4 blocks/CU without any forced clamp.
__global__ __launch_bounds__(BLOCK, 2)
void cmc_kernel(const float* __restrict__ x,
                const float* __restrict__ C,
                const float* __restrict__ G,
                const float* __restrict__ T,
                const float* __restrict__ adap,
                const float* __restrict__ R,
                float* __restrict__ out)
{
    // ct16[j*128 + (i ^ ((j&15)<<2))] = bf16(C[i][j]), diag zeroed.
    __shared__ unsigned short ct16[NNODES * NNODES];   // 32 KB
    __shared__ float m_lds[ROWS_PER_CHUNK][NNODES];    //  8 KB  (total 40 KB)

    const int tid    = threadIdx.x;
    const int lane31 = tid & 31;
    const int lr     = tid >> 5;          // 0..7 (half-wave id)
    const int n0     = lane31 * 4;        // this thread's 4 nodes

    // ---- stage Ct once per block: 4x4 tile transpose, f32 -> bf16 ----
    {
        const int j0 = lane31 * 4;        // j-tile (coalesced source reads)
        const int tb = tid >> 5;
        #pragma unroll
        for (int it = 0; it < 4; ++it) {
            const int i0 = (tb + it * 8) * 4;
            float4 row[4];
            #pragma unroll
            for (int r = 0; r < 4; ++r)
                row[r] = *reinterpret_cast<const float4*>(C + (size_t)(i0 + r) * NNODES + j0);
            #pragma unroll
            for (int k = 0; k < 4; ++k) {
                const int j = j0 + k;
                ushort4 w;
                w.x = (i0 + 0 == j) ? (unsigned short)0 : bf16_((&row[0].x)[k]);
                w.y = (i0 + 1 == j) ? (unsigned short)0 : bf16_((&row[1].x)[k]);
                w.z = (i0 + 2 == j) ? (unsigned short)0 : bf16_((&row[2].x)[k]);
                w.w = (i0 + 3 == j) ? (unsigned short)0 : bf16_((&row[3].x)[k]);
                const int col = i0 ^ ((j & 15) << 2);
                *reinterpret_cast<ushort4*>(&ct16[j * NNODES + col]) = w;
            }
        }
    }

    // ---- per-node params into registers (reused across chunks) ----
    float g[4][12], invT[4][4], sc[4], Rr[4];
    #pragma unroll
    for (int i = 0; i < 4; ++i) {
        int n = n0 + i;
        #pragma unroll
        for (int k = 0; k < 12; ++k) g[i][k] = G[n * 12 + k];
        #pragma unroll
        for (int k = 0; k < 4; ++k) invT[i][k] = 1.0f / T[n * 4 + k];
        sc[i] = 0.1f * sigmoidf_(adap[n]);
        Rr[i] = R[n];
    }

    __syncthreads();   // ct16 visible to all waves (only barrier in the kernel)

    for (int chunk = blockIdx.x; chunk < NCHUNKS; chunk += GRID) {
        const int r0 = chunk * ROWS_PER_CHUNK + lr;
        const int r1 = r0 + 8;

        // ---- load + clip x: 2 rows x 4 nodes x 8 states ----
        float xv[2][32];
        {
            const float4* p0 = reinterpret_cast<const float4*>(x + (size_t)r0 * 1024 + n0 * 8);
            const float4* p1 = reinterpret_cast<const float4*>(x + (size_t)r1 * 1024 + n0 * 8);
            #pragma unroll
            for (int q = 0; q < 8; ++q) {
                float4 v = p0[q];
                xv[0][q * 4 + 0] = clipf_(v.x); xv[0][q * 4 + 1] = clipf_(v.y);
                xv[0][q * 4 + 2] = clipf_(v.z); xv[0][q * 4 + 3] = clipf_(v.w);
            }
            #pragma unroll
            for (int q = 0; q < 8; ++q) {
                float4 v = p1[q];
                xv[1][q * 4 + 0] = clipf_(v.x); xv[1][q * 4 + 1] = clipf_(v.y);
                xv[1][q * 4 + 2] = clipf_(v.z); xv[1][q * 4 + 3] = clipf_(v.w);
            }
        }

        // ---- node means -> LDS (intra-half-wave exchange: rows lr / lr+8 are
        //      written and read only by this half-wave; same-wave DS ordering
        //      makes this safe without a barrier) ----
        {
            float4 ma, mb;
            float* pa = &ma.x; float* pb = &mb.x;
            #pragma unroll
            for (int i = 0; i < 4; ++i) {
                float s0 = 0.0f, s1 = 0.0f;
                #pragma unroll
                for (int k = 0; k < 8; ++k) { s0 += xv[0][i * 8 + k]; s1 += xv[1][i * 8 + k]; }
                pa[i] = s0 * 0.125f; pb[i] = s1 * 0.125f;
            }
            *reinterpret_cast<float4*>(&m_lds[lr][n0])     = ma;
            *reinterpret_cast<float4*>(&m_lds[lr + 8][n0]) = mb;
        }

        // ---- node_input: acc[i] = sum_j m[r][j] * Ct[j][n0+i] ----
        float acc0[4] = {0, 0, 0, 0}, acc1[4] = {0, 0, 0, 0};
        #pragma unroll 8
        for (int j4 = 0; j4 < 32; ++j4) {
            float4 mA = *reinterpret_cast<const float4*>(&m_lds[lr][j4 * 4]);
            float4 mB = *reinterpret_cast<const float4*>(&m_lds[lr + 8][j4 * 4]);
            const float* pmA = &mA.x; const float* pmB = &mB.x;
            #pragma unroll
            for (int c2 = 0; c2 < 4; ++c2) {
                const int j = j4 * 4 + c2;
                const int col = n0 ^ ((j & 15) << 2);
                uint2 cu = *reinterpret_cast<const uint2*>(&ct16[j * NNODES + col]);
                float cv0 = __uint_as_float(cu.x << 16);
                float cv1 = __uint_as_float(cu.x & 0xffff0000u);
                float cv2 = __uint_as_float(cu.y << 16);
                float cv3 = __uint_as_float(cu.y & 0xffff0000u);
                float mv0 = pmA[c2], mv1 = pmB[c2];
                acc0[0] = fmaf(mv0, cv0, acc0[0]);
                acc0[1] = fmaf(mv0, cv1, acc0[1]);
                acc0[2] = fmaf(mv0, cv2, acc0[2]);
                acc0[3] = fmaf(mv0, cv3, acc0[3]);
                acc1[0] = fmaf(mv1, cv0, acc1[0]);
                acc1[1] = fmaf(mv1, cv1, acc1[1]);
                acc1[2] = fmaf(mv1, cv2, acc1[2]);
                acc1[3] = fmaf(mv1, cv3, acc1[3]);
            }
        }

        // ---- epilogue + store ----
        {
            float* o0 = out + (size_t)r0 * 1024 + n0 * 8;
            float* o1 = out + (size_t)r1 * 1024 + n0 * 8;
            #pragma unroll
            for (int i = 0; i < 4; ++i) {
                float f8[8];
                node_update(&xv[0][i * 8], acc0[i], g[i], invT[i], sc[i], Rr[i], f8);
                *reinterpret_cast<float4*>(o0 + i * 8)     = make_float4(f8[0], f8[1], f8[2], f8[3]);
                *reinterpret_cast<float4*>(o0 + i * 8 + 4) = make_float4(f8[4], f8[5], f8[6], f8[7]);
            }
            #pragma unroll
            for (int i = 0; i < 4; ++i) {
                float f8[8];
                node_update(&xv[1][i * 8], acc1[i], g[i], invT[i], sc[i], Rr[i], f8);
                *reinterpret_cast<float4*>(o1 + i * 8)     = make_float4(f8[0], f8[1], f8[2], f8[3]);
                *reinterpret_cast<float4*>(o1 + i * 8 + 4) = make_float4(f8[4], f8[5], f8[6], f8[7]);
            }
        }
        // no barrier: m_lds WAR across chunks is same-wave, handled by lgkmcnt
    }
}

extern "C" void kernel_launch(void* const* d_in, const int* in_sizes, int n_in,
                              void* d_out, int out_size, void* d_ws, size_t ws_size,
                              hipStream_t stream) {
    // setup_inputs order: t, x, node_connectivity, G, T, adaptation, R
    const float* x    = (const float*)d_in[1];
    const float* C    = (const float*)d_in[2];
    const float* G    = (const float*)d_in[3];
    const float* T    = (const float*)d_in[4];
    const float* adap = (const float*)d_in[5];
    const float* R    = (const float*)d_in[6];
    float* out        = (float*)d_out;

    hipLaunchKernelGGL(cmc_kernel, dim3(GRID), dim3(BLOCK), 0, stream,
                       x, C, G, T, adap, R, out);
}

// Round 4
// 64.579 us; speedup vs baseline: 3.6470x; 1.6688x over previous
//
#include <hip/hip_runtime.h>

#define NNODES 128
#define BATCH  32768
#define BLOCK  256                          // 4 waves
#define ROWS_PER_CHUNK 8                    // 4 waves x 2 rows
#define NCHUNKS (BATCH / ROWS_PER_CHUNK)    // 4096
#define GRID   1024                         // 4 blocks/CU, 4 chunks/block

__device__ __forceinline__ float sigmoidf_(float z) {
    return 1.0f / (1.0f + __expf(-z));
}

__device__ __forceinline__ float clipf_(float v) {
    return fminf(fmaxf(v, -100.0f), 100.0f);
}

__device__ __forceinline__ unsigned short bf16_(float f) {
    unsigned u = __float_as_uint(f);
    return (unsigned short)((u + 0x8000u) >> 16);
}

// Per-node epilogue: 8 clipped states + node_input + params -> 8 derivatives.
__device__ __forceinline__ void node_update(const float* xs8, float ni,
                                            const float* gi, const float* invTi,
                                            float sci, float Ri, float* f8) {
    float S0 = sigmoidf_(Ri * xs8[0]) - 0.5f;
    float S2 = sigmoidf_(Ri * xs8[2]) - 0.5f;
    float S4 = sigmoidf_(Ri * xs8[4]) - 0.5f;
    float S6 = sigmoidf_(Ri * xs8[6]) - 0.5f;
    float u1 = ni - gi[0] * S0 - gi[1] * S2 - gi[2]  * S4;
    float u3 = ni + gi[7] * S0 - gi[6] * S2 - gi[11] * S4;
    float u5 = ni + gi[4] * S0 + gi[10] * S2 - gi[3] * S4 + gi[5] * S6;
    float u7 = ni - gi[8] * S4 - gi[9] * S6;
    f8[0] = sci * xs8[1];
    f8[1] = sci * (u1 - 2.0f * xs8[1] - xs8[0] * invTi[0]) * invTi[0];
    f8[2] = sci * xs8[3];
    f8[3] = sci * (u3 - 2.0f * xs8[3] - xs8[2] * invTi[1]) * invTi[1];
    f8[4] = sci * xs8[5];
    f8[5] = sci * (u5 - 2.0f * xs8[5] - xs8[4] * invTi[2]) * invTi[2];
    f8[6] = sci * xs8[7];
    f8[7] = sci * (u7 - 2.0f * xs8[7] - xs8[6] * invTi[3]) * invTi[3];
}

__global__ __launch_bounds__(BLOCK, 2)   // 128-VGPR budget; body needs ~100
void cmc_kernel(const float* __restrict__ x,
                const float* __restrict__ C,
                const float* __restrict__ G,
                const float* __restrict__ T,
                const float* __restrict__ adap,
                const float* __restrict__ R,
                float* __restrict__ out)
{
    // ct16[j*128 + (i ^ ((j&15)<<2))] = bf16(C[i][j]), diag zeroed.
    // matmul read: lane reads b32 at col=2*lane^swz -> lanes 0..31 cover all
    // 32 banks (2-way over the wave = free).
    __shared__ unsigned short ct16[NNODES * NNODES];   // 32 KB
    __shared__ float m_lds[4][2][NNODES];              //  4 KB (per-wave private)

    const int tid  = threadIdx.x;
    const int lane = tid & 63;
    const int w    = tid >> 6;            // wave 0..3
    const int nA   = 2 * lane;            // this lane's nodes: nA, nA+1

    // ---- stage Ct once per block: 4x4 tile transpose, f32 -> bf16 ----
    {
        const int j0 = (tid & 31) * 4;    // coalesced source reads
        const int tb = tid >> 5;          // 0..7
        #pragma unroll
        for (int it = 0; it < 4; ++it) {
            const int i0 = (tb + it * 8) * 4;
            float4 row[4];
            #pragma unroll
            for (int r = 0; r < 4; ++r)
                row[r] = *reinterpret_cast<const float4*>(C + (size_t)(i0 + r) * NNODES + j0);
            #pragma unroll
            for (int k = 0; k < 4; ++k) {
                const int j = j0 + k;
                ushort4 wv;
                wv.x = (i0 + 0 == j) ? (unsigned short)0 : bf16_((&row[0].x)[k]);
                wv.y = (i0 + 1 == j) ? (unsigned short)0 : bf16_((&row[1].x)[k]);
                wv.z = (i0 + 2 == j) ? (unsigned short)0 : bf16_((&row[2].x)[k]);
                wv.w = (i0 + 3 == j) ? (unsigned short)0 : bf16_((&row[3].x)[k]);
                const int col = i0 ^ ((j & 15) << 2);
                *reinterpret_cast<ushort4*>(&ct16[j * NNODES + col]) = wv;
            }
        }
    }

    // ---- per-node params (2 nodes/lane) ----
    float g[2][12], invT[2][4], sc[2], Rr[2];
    #pragma unroll
    for (int i = 0; i < 2; ++i) {
        int n = nA + i;
        #pragma unroll
        for (int k = 0; k < 12; ++k) g[i][k] = G[n * 12 + k];
        #pragma unroll
        for (int k = 0; k < 4; ++k) invT[i][k] = 1.0f / T[n * 4 + k];
        sc[i] = 0.1f * sigmoidf_(adap[n]);
        Rr[i] = R[n];
    }

    __syncthreads();   // ct16 visible; ONLY barrier in the kernel

    for (int chunk = blockIdx.x; chunk < NCHUNKS; chunk += GRID) {
        const int r0 = chunk * ROWS_PER_CHUNK + 2 * w;   // wave's rows: r0, r0+1

        // ---- load + clip x: 2 rows, this lane's 16 columns (own nodes) ----
        float xv[2][16];
        {
            const float4* p0 = reinterpret_cast<const float4*>(x + (size_t)r0 * 1024 + lane * 16);
            const float4* p1 = reinterpret_cast<const float4*>(x + (size_t)(r0 + 1) * 1024 + lane * 16);
            #pragma unroll
            for (int q = 0; q < 4; ++q) {
                float4 v = p0[q];
                xv[0][q * 4 + 0] = clipf_(v.x); xv[0][q * 4 + 1] = clipf_(v.y);
                xv[0][q * 4 + 2] = clipf_(v.z); xv[0][q * 4 + 3] = clipf_(v.w);
            }
            #pragma unroll
            for (int q = 0; q < 4; ++q) {
                float4 v = p1[q];
                xv[1][q * 4 + 0] = clipf_(v.x); xv[1][q * 4 + 1] = clipf_(v.y);
                xv[1][q * 4 + 2] = clipf_(v.z); xv[1][q * 4 + 3] = clipf_(v.w);
            }
        }

        // ---- node means (lane-local!) -> per-wave-private LDS row ----
        #pragma unroll
        for (int rr = 0; rr < 2; ++rr) {
            float s0 = 0.0f, s1 = 0.0f;
            #pragma unroll
            for (int k = 0; k < 8; ++k) { s0 += xv[rr][k]; s1 += xv[rr][8 + k]; }
            float2 mv = make_float2(s0 * 0.125f, s1 * 0.125f);
            *reinterpret_cast<float2*>(&m_lds[w][rr][nA]) = mv;
        }
        // same-wave write->read: ordered by lgkmcnt, no barrier needed

        // ---- node_input: acc[rr][i] = sum_j m[rr][j] * Ct[j][nA+i] ----
        float acc00 = 0.f, acc01 = 0.f, acc10 = 0.f, acc11 = 0.f;
        #pragma unroll 4
        for (int j4 = 0; j4 < 32; ++j4) {
            float4 mA = *reinterpret_cast<const float4*>(&m_lds[w][0][j4 * 4]);  // broadcast
            float4 mB = *reinterpret_cast<const float4*>(&m_lds[w][1][j4 * 4]);  // broadcast
            const float* pmA = &mA.x; const float* pmB = &mB.x;
            #pragma unroll
            for (int c = 0; c < 4; ++c) {
                const int j   = j4 * 4 + c;
                const int col = nA ^ ((j & 15) << 2);
                unsigned cu = *reinterpret_cast<const unsigned*>(&ct16[j * NNODES + col]);
                float ce = __uint_as_float(cu << 16);          // node nA
                float co = __uint_as_float(cu & 0xffff0000u);  // node nA+1
                acc00 = fmaf(pmA[c], ce, acc00);
                acc01 = fmaf(pmA[c], co, acc01);
                acc10 = fmaf(pmB[c], ce, acc10);
                acc11 = fmaf(pmB[c], co, acc11);
            }
        }

        // ---- epilogue + store: 2 rows x 2 nodes ----
        {
            float* o0 = out + (size_t)r0 * 1024 + lane * 16;
            float* o1 = out + (size_t)(r0 + 1) * 1024 + lane * 16;
            float f8[8];
            node_update(&xv[0][0], acc00, g[0], invT[0], sc[0], Rr[0], f8);
            *reinterpret_cast<float4*>(o0)      = make_float4(f8[0], f8[1], f8[2], f8[3]);
            *reinterpret_cast<float4*>(o0 + 4)  = make_float4(f8[4], f8[5], f8[6], f8[7]);
            node_update(&xv[0][8], acc01, g[1], invT[1], sc[1], Rr[1], f8);
            *reinterpret_cast<float4*>(o0 + 8)  = make_float4(f8[0], f8[1], f8[2], f8[3]);
            *reinterpret_cast<float4*>(o0 + 12) = make_float4(f8[4], f8[5], f8[6], f8[7]);
            node_update(&xv[1][0], acc10, g[0], invT[0], sc[0], Rr[0], f8);
            *reinterpret_cast<float4*>(o1)      = make_float4(f8[0], f8[1], f8[2], f8[3]);
            *reinterpret_cast<float4*>(o1 + 4)  = make_float4(f8[4], f8[5], f8[6], f8[7]);
            node_update(&xv[1][8], acc11, g[1], invT[1], sc[1], Rr[1], f8);
            *reinterpret_cast<float4*>(o1 + 8)  = make_float4(f8[0], f8[1], f8[2], f8[3]);
            *reinterpret_cast<float4*>(o1 + 12) = make_float4(f8[4], f8[5], f8[6], f8[7]);
        }
        // m_lds[w] is wave-private: WAR across chunks is same-wave, safe
    }
}

extern "C" void kernel_launch(void* const* d_in, const int* in_sizes, int n_in,
                              void* d_out, int out_size, void* d_ws, size_t ws_size,
                              hipStream_t stream) {
    // setup_inputs order: t, x, node_connectivity, G, T, adaptation, R
    const float* x    = (const float*)d_in[1];
    const float* C    = (const float*)d_in[2];
    const float* G    = (const float*)d_in[3];
    const float* T    = (const float*)d_in[4];
    const float* adap = (const float*)d_in[5];
    const float* R    = (const float*)d_in[6];
    float* out        = (float*)d_out;

    hipLaunchKernelGGL(cmc_kernel, dim3(GRID), dim3(BLOCK), 0, stream,
                       x, C, G, T, adap, R, out);
}